// Round 1
// baseline (348.600 us; speedup 1.0000x reference)
//
#include <hip/hip_runtime.h>
#include <math.h>

// Problem constants
#define NB 2
#define CIN 16
#define COUT 8
#define DD 96
#define TDIM 256
#define NE 8
#define VOX (DD*DD*DD)          // 884736
#define OUT_ELEMS (NB*COUT*VOX) // 14155776

// Workspace layout (floats):
// ws[0 .. 6911]   : mixed conv weights, layout [b][ci][tap][co], tap = dz*9+dy*3+dx
// ws[6912 .. 6927]: a[b][co]  = 1 + gamma
// ws[6928 .. 6943]: d[b][co]  = cb * a
#define WS_W 0
#define WS_A 6912
#define WS_D 6928

__global__ void setup_kernel(const float* __restrict__ text,  // [2,256]
                             const float* __restrict__ wb,    // [E,COUT,CIN,27]
                             const float* __restrict__ bb,    // [E,COUT]
                             const float* __restrict__ rw1, const float* __restrict__ rb1,
                             const float* __restrict__ rw2, const float* __restrict__ rb2,
                             const float* __restrict__ mw1, const float* __restrict__ mb1,
                             const float* __restrict__ mw2, const float* __restrict__ mb2,
                             float* __restrict__ dout_tail,   // d_out + OUT_ELEMS
                             float* __restrict__ ws)
{
    __shared__ float h[NB][64], g[NB][64], logits[NB][NE], rw[NB][NE];
    const int t = threadIdx.x;

    // --- hidden layers of both MLPs (128 + 128 dot-products of length 256) ---
    if (t < 128) {
        const int b = t >> 6, j = t & 63;
        float acc = rb1[j];
        for (int k = 0; k < TDIM; ++k) acc = fmaf(text[b*TDIM + k], rw1[k*64 + j], acc);
        h[b][j] = (acc >= 0.f) ? acc : 0.1f * acc;
    } else {
        const int tt = t - 128, b = tt >> 6, j = tt & 63;
        float acc = mb1[j];
        for (int k = 0; k < TDIM; ++k) acc = fmaf(text[b*TDIM + k], mw1[k*64 + j], acc);
        g[b][j] = (acc >= 0.f) ? acc : 0.1f * acc;
    }
    __syncthreads();

    // --- router logits ---
    if (t < NB*NE) {
        const int b = t >> 3, e = t & 7;
        float acc = rb2[e];
        for (int k = 0; k < 64; ++k) acc = fmaf(h[b][k], rw2[k*NE + e], acc);
        logits[b][e] = acc;
        dout_tail[t] = acc;                 // router_logits output
    }
    __syncthreads();

    // --- softmax -> routing weights ---
    if (t < NB*NE) {
        const int b = t >> 3, e = t & 7;
        float mx = logits[b][0];
        for (int k = 1; k < NE; ++k) mx = fmaxf(mx, logits[b][k]);
        float s = 0.f;
        for (int k = 0; k < NE; ++k) s += expf(logits[b][k] - mx);
        const float w = expf(logits[b][e] - mx) / s;
        rw[b][e] = w;
        dout_tail[NB*NE + t] = w;           // routing_weights output
    }
    __syncthreads();

    // --- gamma (modulator head), bias mix, fused epilogue constants ---
    if (t < NB*COUT) {
        const int b = t >> 3, co = t & 7;
        float acc = mb2[co];
        for (int k = 0; k < 64; ++k) acc = fmaf(g[b][k], mw2[k*COUT + co], acc);
        const float gamma = 1.f / (1.f + expf(-acc));
        const float a = 1.f + gamma;
        float cb = 0.f;
        for (int e = 0; e < NE; ++e) cb = fmaf(rw[b][e], bb[e*COUT + co], cb);
        ws[WS_A + t] = a;
        ws[WS_D + t] = cb * a;
    }

    // --- expert-mixed conv weights, transposed to [b][ci][tap][co] ---
    for (int idx = t; idx < NB*CIN*27*COUT; idx += blockDim.x) {
        const int b = idx / (CIN*27*COUT);
        const int j = idx % (CIN*27*COUT);
        const int co = j & 7;
        const int q = j >> 3;
        const int tap = q % 27;
        const int ci = q / 27;
        float acc = 0.f;
        for (int e = 0; e < NE; ++e)
            acc = fmaf(rw[b][e], wb[((e*COUT + co)*CIN + ci)*27 + tap], acc);
        ws[WS_W + idx] = acc;
    }
}

// Conv: thread = 6-wide x strip for all 8 Couts. Block = 16 x-chunks x 16 y-rows.
// Grid = (6 y-slabs, 96 z, 2 b).
__global__ __launch_bounds__(256) void conv_kernel(
    const float* __restrict__ x,   // [2,16,96,96,96]
    const float* __restrict__ ws,
    float* __restrict__ out)       // [2,8,96,96,96]
{
    const int t  = threadIdx.x;
    const int cx = t & 15;         // x chunk 0..15
    const int ty = t >> 4;         // 0..15
    const int y  = blockIdx.x * 16 + ty;
    const int z  = blockIdx.y;
    const int b  = blockIdx.z;
    const int x0 = cx * 6;

    const float* __restrict__ wsw = ws + WS_W + b * (CIN*27*COUT);

    float acc[COUT][6];
    #pragma unroll
    for (int co = 0; co < COUT; ++co)
        #pragma unroll
        for (int i = 0; i < 6; ++i) acc[co][i] = 0.f;

    const float* __restrict__ xb = x + b * CIN * VOX;

    for (int ci = 0; ci < CIN; ++ci) {
        const float* __restrict__ xc  = xb + ci * VOX;
        const float* __restrict__ wci = wsw + ci * (27*COUT);
        #pragma unroll
        for (int dz = 0; dz < 3; ++dz) {
            const int zz = z + dz - 1;
            if (zz < 0 || zz >= DD) continue;
            #pragma unroll
            for (int dy = 0; dy < 3; ++dy) {
                const int yy = y + dy - 1;
                if (yy < 0 || yy >= DD) continue;
                const float* __restrict__ row = xc + (zz*DD + yy)*DD + x0;
                float xv[8];
                xv[0] = (cx > 0) ? row[-1] : 0.f;
                #pragma unroll
                for (int i = 0; i < 6; ++i) xv[i+1] = row[i];
                xv[7] = (cx < 15) ? row[6] : 0.f;
                const float* __restrict__ wrow = wci + (dz*3 + dy)*3*COUT;
                #pragma unroll
                for (int dx = 0; dx < 3; ++dx) {
                    #pragma unroll
                    for (int co = 0; co < COUT; ++co) {
                        const float w = wrow[dx*COUT + co];
                        #pragma unroll
                        for (int i = 0; i < 6; ++i)
                            acc[co][i] = fmaf(xv[i + dx], w, acc[co][i]);
                    }
                }
            }
        }
    }

    // epilogue: out = acc * a + d   (d = cb*a folds bias; a = 1+gamma)
    const int sp = (z*DD + y)*DD + x0;
    #pragma unroll
    for (int co = 0; co < COUT; ++co) {
        const float a = ws[WS_A + b*COUT + co];
        const float d = ws[WS_D + b*COUT + co];
        float* __restrict__ op = out + (b*COUT + co) * VOX + sp;
        #pragma unroll
        for (int i = 0; i < 6; ++i) op[i] = fmaf(acc[co][i], a, d);
    }
}

extern "C" void kernel_launch(void* const* d_in, const int* in_sizes, int n_in,
                              void* d_out, int out_size, void* d_ws, size_t ws_size,
                              hipStream_t stream) {
    const float* x    = (const float*)d_in[0];
    const float* text = (const float*)d_in[1];
    const float* wb   = (const float*)d_in[2];
    const float* bb   = (const float*)d_in[3];
    const float* rw1  = (const float*)d_in[4];
    const float* rb1  = (const float*)d_in[5];
    const float* rw2  = (const float*)d_in[6];
    const float* rb2  = (const float*)d_in[7];
    const float* mw1  = (const float*)d_in[8];
    const float* mb1  = (const float*)d_in[9];
    const float* mw2  = (const float*)d_in[10];
    const float* mb2  = (const float*)d_in[11];

    float* out = (float*)d_out;
    float* ws  = (float*)d_ws;

    setup_kernel<<<1, 256, 0, stream>>>(text, wb, bb, rw1, rb1, rw2, rb2,
                                        mw1, mb1, mw2, mb2,
                                        out + OUT_ELEMS, ws);

    conv_kernel<<<dim3(6, DD, NB), 256, 0, stream>>>(x, ws, out);
}

// Round 2
// 310.143 us; speedup vs baseline: 1.1240x; 1.1240x over previous
//
#include <hip/hip_runtime.h>
#include <math.h>

// Problem constants
#define NB 2
#define CIN 16
#define COUT 8
#define DD 96
#define TDIM 256
#define NE 8
#define VOX (DD*DD*DD)          // 884736
#define OUT_ELEMS (NB*COUT*VOX) // 14155776

// LDS tile: 16x x 16y x 2z outputs, halo +1 each side -> 18 x 18 x 4 voxels
#define LX 18
#define LY 18
#define LZ 4
#define NVOXT (LX*LY*LZ)        // 1296 voxels
#define HALF_BYTES (NVOXT*16)   // 20736 B per ci-half ([vox][8ci] f16 = 16 B slots)
#define NSLOT (2*NVOXT)         // 2592 16-B slots total

// Workspace layout:
//   bytes [0, 28672): B-fragment table, f16 [b][chunk 14][lane 64][j 8]
//   float index 7168..7183 : a[b][co] = 1 + gamma
//   float index 7184..7199 : d[b][co] = cb * a
#define WS_A_F 7168
#define WS_D_F 7184

typedef _Float16 f16x8 __attribute__((ext_vector_type(8)));
typedef float f32x4 __attribute__((ext_vector_type(4)));

// K-chunk geometry: chunk c covers taps (even,odd) with per-lane select p = (lane>>4)&1.
//  c in [0,9):  even tap (dz=c/3, dy=c%3, dx=0), odd = dx=1  (delta +1 vox = 16 B)
//  c in [9,12): even tap (dz=c-9, dy=0, dx=2),  odd = dy=1  (delta +18 vox = 288 B)
//  c == 12:     even tap (dz=0, dy=2, dx=2),    odd = dz=1  (delta +324 vox = 5184 B)
//  c == 13:     even tap (2,2,2), odd = zero weights (reads aliased, B=0)
// OFFB[c] = even-tap voxel offset * 16 bytes, offsets vox = dz*324 + dy*18 + dx
__constant__ int OFFB_dummy; // (table kept constexpr in-kernel)

__global__ void setup_kernel(const float* __restrict__ text,  // [2,256]
                             const float* __restrict__ wb,    // [E,COUT,CIN,27]
                             const float* __restrict__ bb,    // [E,COUT]
                             const float* __restrict__ rw1, const float* __restrict__ rb1,
                             const float* __restrict__ rw2, const float* __restrict__ rb2,
                             const float* __restrict__ mw1, const float* __restrict__ mb1,
                             const float* __restrict__ mw2, const float* __restrict__ mb2,
                             float* __restrict__ dout_tail,   // d_out + OUT_ELEMS
                             void* __restrict__ ws)
{
    __shared__ float h[NB][64], g[NB][64], logits[NB][NE], rw[NB][NE];
    const int t = threadIdx.x;
    float* wsf = (float*)ws;

    // --- hidden layers of both MLPs ---
    if (t < 128) {
        const int b = t >> 6, j = t & 63;
        float acc = rb1[j];
        for (int k = 0; k < TDIM; ++k) acc = fmaf(text[b*TDIM + k], rw1[k*64 + j], acc);
        h[b][j] = (acc >= 0.f) ? acc : 0.1f * acc;
    } else {
        const int tt = t - 128, b = tt >> 6, j = tt & 63;
        float acc = mb1[j];
        for (int k = 0; k < TDIM; ++k) acc = fmaf(text[b*TDIM + k], mw1[k*64 + j], acc);
        g[b][j] = (acc >= 0.f) ? acc : 0.1f * acc;
    }
    __syncthreads();

    // --- router logits ---
    if (t < NB*NE) {
        const int b = t >> 3, e = t & 7;
        float acc = rb2[e];
        for (int k = 0; k < 64; ++k) acc = fmaf(h[b][k], rw2[k*NE + e], acc);
        logits[b][e] = acc;
        dout_tail[t] = acc;                 // router_logits output
    }
    __syncthreads();

    // --- softmax -> routing weights ---
    if (t < NB*NE) {
        const int b = t >> 3, e = t & 7;
        float mx = logits[b][0];
        for (int k = 1; k < NE; ++k) mx = fmaxf(mx, logits[b][k]);
        float s = 0.f;
        for (int k = 0; k < NE; ++k) s += expf(logits[b][k] - mx);
        const float w = expf(logits[b][e] - mx) / s;
        rw[b][e] = w;
        dout_tail[NB*NE + t] = w;           // routing_weights output
    }
    __syncthreads();

    // --- gamma, bias mix, fused epilogue constants ---
    if (t < NB*COUT) {
        const int b = t >> 3, co = t & 7;
        float acc = mb2[co];
        for (int k = 0; k < 64; ++k) acc = fmaf(g[b][k], mw2[k*COUT + co], acc);
        const float gamma = 1.f / (1.f + expf(-acc));
        const float a = 1.f + gamma;
        float cb = 0.f;
        for (int e = 0; e < NE; ++e) cb = fmaf(rw[b][e], bb[e*COUT + co], cb);
        wsf[WS_A_F + t] = a;
        wsf[WS_D_F + t] = cb * a;
    }

    // --- bake per-lane MFMA B-fragments (f16) ---
    // idx = ((b*14 + c)*64 + lane)*8 + j
    for (int idx = t; idx < 2*14*64*8; idx += 256) {
        const int b  = (idx >= 7168) ? 1 : 0;
        const int r  = idx - b*7168;
        const int c  = r >> 9;
        const int l  = (r >> 3) & 63;
        const int j  = idx & 7;
        const int q  = l >> 4;
        const int n  = l & 15;       // output column = cout (cols 8..15 zero)
        const int p  = q & 1;        // tap parity within chunk
        const int ci = (q >> 1)*8 + j;
        int tap;
        if (c < 9)        tap = (c/3)*9 + (c%3)*3 + p;
        else if (c < 12)  tap = (c-9)*9 + p*3 + 2;
        else if (c == 12) tap = p*9 + 8;
        else              tap = p ? -1 : 26;
        float v = 0.f;
        if (n < 8 && tap >= 0) {
            for (int e = 0; e < NE; ++e)
                v = fmaf(rw[b][e], wb[((e*COUT + n)*CIN + ci)*27 + tap], v);
        }
        ((_Float16*)ws)[idx] = (_Float16)v;
    }
}

// Implicit-GEMM conv via f16 MFMA. Block = 256 thr (4 waves), tile 16x*16y*2z.
// Grid = (36 xy-tiles, 48 z-tiles, 2 b).
__global__ __launch_bounds__(256) void conv_mfma(
    const float* __restrict__ x,   // [2,16,96,96,96] f32
    const void*  __restrict__ ws,
    float* __restrict__ out)       // [2,8,96,96,96] f32
{
    __shared__ char lds[2*HALF_BYTES];  // [ci_half][vox 1296][8ci f16] = 41472 B
    const int tid  = threadIdx.x;
    const int lane = tid & 63;
    const int wv   = tid >> 6;
    const int b    = blockIdx.z;
    const int z0   = blockIdx.y * 2;
    const int xt   = blockIdx.x % 6;
    const int yt   = blockIdx.x / 6;
    const int x0   = xt * 16, y0 = yt * 16;

    // --- load per-lane B fragments (14 x 16 B, coalesced) ---
    const f16x8* __restrict__ bfp = (const f16x8*)ws;
    f16x8 bfrag[14];
    #pragma unroll
    for (int c = 0; c < 14; ++c)
        bfrag[c] = bfp[(b*14 + c)*64 + lane];

    // --- stage x tile -> LDS (f32->f16, [half][vox][8ci], b128 writes) ---
    const float* __restrict__ xb = x + (size_t)b * CIN * VOX;
    for (int s = tid; s < NSLOT; s += 256) {
        const int half = (s >= NVOXT) ? 1 : 0;
        const int v  = s - half * NVOXT;
        const int lz = v / (LX*LY);
        const int r1 = v - lz * (LX*LY);
        const int ly = r1 / LX;
        const int lx = r1 - ly * LX;
        const int zg = z0 - 1 + lz, yg = y0 - 1 + ly, xg = x0 - 1 + lx;
        const bool ok = ((unsigned)zg < 96u) & ((unsigned)yg < 96u) & ((unsigned)xg < 96u);
        const int zc = ok ? zg : 0, yc = ok ? yg : 0, xc = ok ? xg : 0;
        const float* __restrict__ p = xb + (size_t)(half*8) * VOX + (zc*DD + yc)*DD + xc;
        f16x8 hv;
        #pragma unroll
        for (int i = 0; i < 8; ++i) {
            const float val = p[(size_t)i * VOX];
            hv[i] = (_Float16)(ok ? val : 0.0f);
        }
        *reinterpret_cast<f16x8*>(&lds[s * 16]) = hv;
    }
    __syncthreads();

    // --- MFMA main loop ---
    const int q    = lane >> 4;
    const int m    = lane & 15;    // A-row (x offset) AND D-col (cout) index
    const int pbit = q & 1;
    const int hbit = q >> 1;

    const float* wsf = (const float*)ws;
    const float a_n = wsf[WS_A_F + b*8 + (m & 7)];
    const float d_n = wsf[WS_D_F + b*8 + (m & 7)];

    // even-tap byte offsets per chunk (vox*16)
    constexpr int OFFB[14] = {0,288,576,5184,5472,5760,10368,10656,10944,
                              32,5216,10400,608,10976};

    const int com = hbit*HALF_BYTES + m*16;
    const int dA = pbit*16, dB = pbit*288, dC = pbit*5184;

    #pragma unroll
    for (int t = 0; t < 8; ++t) {
        const int zi = t & 1;
        const int yi = wv*4 + (t >> 1);
        const char* __restrict__ base = &lds[(zi*(LX*LY) + yi*LX)*16 + com];

        f16x8 af[14];
        #pragma unroll
        for (int c = 0; c < 9; ++c)  af[c] = *(const f16x8*)(base + dA + OFFB[c]);
        #pragma unroll
        for (int c = 9; c < 12; ++c) af[c] = *(const f16x8*)(base + dB + OFFB[c]);
        af[12] = *(const f16x8*)(base + dC + OFFB[12]);
        af[13] = *(const f16x8*)(base + OFFB[13]);   // odd lanes alias tap26, B=0

        f32x4 acc0 = {0.f,0.f,0.f,0.f}, acc1 = {0.f,0.f,0.f,0.f};
        #pragma unroll
        for (int c = 0; c < 14; c += 2) {
            acc0 = __builtin_amdgcn_mfma_f32_16x16x32_f16(af[c],   bfrag[c],   acc0, 0, 0, 0);
            acc1 = __builtin_amdgcn_mfma_f32_16x16x32_f16(af[c+1], bfrag[c+1], acc1, 0, 0, 0);
        }

        if (m < 8) {  // D cols 8..15 are padding
            const int zz = z0 + zi, yy = y0 + yi;
            float* __restrict__ op = out + (size_t)(b*COUT + m)*VOX
                                        + (size_t)(zz*DD + yy)*DD + x0 + q*4;
            f32x4 res;
            #pragma unroll
            for (int r = 0; r < 4; ++r) res[r] = fmaf(acc0[r] + acc1[r], a_n, d_n);
            *reinterpret_cast<f32x4*>(op) = res;   // rows q*4+r = x offsets, 16-B aligned
        }
    }
}

extern "C" void kernel_launch(void* const* d_in, const int* in_sizes, int n_in,
                              void* d_out, int out_size, void* d_ws, size_t ws_size,
                              hipStream_t stream) {
    const float* x    = (const float*)d_in[0];
    const float* text = (const float*)d_in[1];
    const float* wb   = (const float*)d_in[2];
    const float* bb   = (const float*)d_in[3];
    const float* rw1  = (const float*)d_in[4];
    const float* rb1  = (const float*)d_in[5];
    const float* rw2  = (const float*)d_in[6];
    const float* rb2  = (const float*)d_in[7];
    const float* mw1  = (const float*)d_in[8];
    const float* mb1  = (const float*)d_in[9];
    const float* mw2  = (const float*)d_in[10];
    const float* mb2  = (const float*)d_in[11];

    float* out = (float*)d_out;

    setup_kernel<<<1, 256, 0, stream>>>(text, wb, bb, rw1, rb1, rw2, rb2,
                                        mw1, mb1, mw2, mb2,
                                        out + OUT_ELEMS, d_ws);

    conv_mfma<<<dim3(36, 48, NB), 256, 0, stream>>>(x, d_ws, out);
}

// Round 3
// 290.023 us; speedup vs baseline: 1.2020x; 1.0694x over previous
//
#include <hip/hip_runtime.h>
#include <math.h>

// Problem constants
#define NB 2
#define CIN 16
#define COUT 8
#define DD 96
#define TDIM 256
#define NE 8
#define VOX (DD*DD*DD)          // 884736
#define OUT_ELEMS (NB*COUT*VOX) // 14155776

// ---- workspace layout ----
// [0, XT_BYTES): xt, f16 channels-last [b][vox][ci16] = 32 B / voxel
// [XT_BYTES, +28672): B-fragment table f16 [b][chunk14][lane64][j8]
// then floats at f32-offset 7168: a[b][co]; 7184: d[b][co]
#define XT_BYTES ((size_t)NB * VOX * 32)
#define WS_A_F 7168
#define WS_D_F 7184

// conv LDS tile: 16x*16y*3z outputs, halo -> 18*18*5 voxels
#define LX 18
#define PLANE (LX*LX)           // 324
#define NVX (PLANE*5)           // 1620
#define HALFB (NVX*16)          // 25920 B per ci-half ([vox][8ci] f16)

typedef _Float16 f16x8 __attribute__((ext_vector_type(8)));
typedef _Float16 f16x4 __attribute__((ext_vector_type(4)));
typedef float f32x4 __attribute__((ext_vector_type(4)));

// ---------------- setup: MLPs + B-fragment baking ----------------
__global__ void setup_kernel(const float* __restrict__ text,
                             const float* __restrict__ wb,    // [E,COUT,CIN,27]
                             const float* __restrict__ bb,    // [E,COUT]
                             const float* __restrict__ rw1, const float* __restrict__ rb1,
                             const float* __restrict__ rw2, const float* __restrict__ rb2,
                             const float* __restrict__ mw1, const float* __restrict__ mb1,
                             const float* __restrict__ mw2, const float* __restrict__ mb2,
                             float* __restrict__ dout_tail,   // d_out + OUT_ELEMS
                             char* __restrict__ tab)          // ws + XT_BYTES
{
    __shared__ float h[NB][64], g[NB][64], logits[NB][NE], rw[NB][NE];
    const int t = threadIdx.x;
    float* tabf = (float*)tab;

    if (t < 128) {
        const int b = t >> 6, j = t & 63;
        float acc = rb1[j];
        for (int k = 0; k < TDIM; ++k) acc = fmaf(text[b*TDIM + k], rw1[k*64 + j], acc);
        h[b][j] = (acc >= 0.f) ? acc : 0.1f * acc;
    } else {
        const int tt = t - 128, b = tt >> 6, j = tt & 63;
        float acc = mb1[j];
        for (int k = 0; k < TDIM; ++k) acc = fmaf(text[b*TDIM + k], mw1[k*64 + j], acc);
        g[b][j] = (acc >= 0.f) ? acc : 0.1f * acc;
    }
    __syncthreads();

    if (t < NB*NE) {
        const int b = t >> 3, e = t & 7;
        float acc = rb2[e];
        for (int k = 0; k < 64; ++k) acc = fmaf(h[b][k], rw2[k*NE + e], acc);
        logits[b][e] = acc;
        dout_tail[t] = acc;                 // router_logits
    }
    __syncthreads();

    if (t < NB*NE) {
        const int b = t >> 3, e = t & 7;
        float mx = logits[b][0];
        for (int k = 1; k < NE; ++k) mx = fmaxf(mx, logits[b][k]);
        float s = 0.f;
        for (int k = 0; k < NE; ++k) s += expf(logits[b][k] - mx);
        const float w = expf(logits[b][e] - mx) / s;
        rw[b][e] = w;
        dout_tail[NB*NE + t] = w;           // routing_weights
    }
    __syncthreads();

    if (t < NB*COUT) {
        const int b = t >> 3, co = t & 7;
        float acc = mb2[co];
        for (int k = 0; k < 64; ++k) acc = fmaf(g[b][k], mw2[k*COUT + co], acc);
        const float gamma = 1.f / (1.f + expf(-acc));
        const float a = 1.f + gamma;
        float cb = 0.f;
        for (int e = 0; e < NE; ++e) cb = fmaf(rw[b][e], bb[e*COUT + co], cb);
        tabf[WS_A_F + t] = a;
        tabf[WS_D_F + t] = cb * a;
    }

    // bake per-lane MFMA B-fragments: idx = ((b*14 + c)*64 + lane)*8 + j
    for (int idx = t; idx < 2*14*64*8; idx += 256) {
        const int b  = (idx >= 7168) ? 1 : 0;
        const int r  = idx - b*7168;
        const int c  = r >> 9;
        const int l  = (r >> 3) & 63;
        const int j  = idx & 7;
        const int q  = l >> 4;
        const int n  = l & 15;       // output column = cout (cols 8..15 zero)
        const int p  = q & 1;        // tap parity within chunk
        const int ci = (q >> 1)*8 + j;
        int tap;
        if (c < 9)        tap = (c/3)*9 + (c%3)*3 + p;
        else if (c < 12)  tap = (c-9)*9 + p*3 + 2;
        else if (c == 12) tap = p*9 + 8;
        else              tap = p ? -1 : 26;
        float v = 0.f;
        if (n < 8 && tap >= 0) {
            for (int e = 0; e < NE; ++e)
                v = fmaf(rw[b][e], wb[((e*COUT + n)*CIN + ci)*27 + tap], v);
        }
        ((_Float16*)tab)[idx] = (_Float16)v;
    }
}

// ---------------- transpose: x f32 [b][ci][vox] -> xt f16 [b][vox][ci16] ----------------
#define TV 1024
__global__ __launch_bounds__(256) void transpose_kernel(
    const float* __restrict__ x, _Float16* __restrict__ xt)
{
    __shared__ _Float16 buf[CIN][TV];    // 32 KB, planar per-ci
    const int t  = threadIdx.x;
    const int b  = blockIdx.y;
    const int v0 = blockIdx.x * TV;
    const float* __restrict__ xb = x + (size_t)b * CIN * VOX + v0;

    // phase A: coalesced float4 reads per ci, f16x4 LDS writes (8-B lane stride)
    #pragma unroll
    for (int ci = 0; ci < CIN; ++ci) {
        const float4 f = ((const float4*)(xb + (size_t)ci * VOX))[t];
        f16x4 hv;
        hv[0] = (_Float16)f.x; hv[1] = (_Float16)f.y;
        hv[2] = (_Float16)f.z; hv[3] = (_Float16)f.w;
        *(f16x4*)&buf[ci][t*4] = hv;
    }
    __syncthreads();

    // phase B: gather 16 ci per voxel, write 32 B contiguous
    #pragma unroll
    for (int i = 0; i < TV/256; ++i) {
        const int v = i*256 + t;
        union { _Float16 h[16]; uint4 u[2]; } o;
        #pragma unroll
        for (int ci = 0; ci < CIN; ++ci) o.h[ci] = buf[ci][v];
        uint4* __restrict__ dst = (uint4*)(xt + (size_t)(b*VOX + v0 + v) * 16);
        dst[0] = o.u[0];
        dst[1] = o.u[1];
    }
}

// ---------------- conv: implicit-GEMM f16 MFMA ----------------
// Block = 256 thr (4 waves), tile 16x*16y*3z. Grid = (36, 32, 2).
__global__ __launch_bounds__(256) void conv_mfma(
    const _Float16* __restrict__ xt,   // [b][vox][16] f16
    const char* __restrict__ tab,
    float* __restrict__ out)
{
    __shared__ char lds[2*HALFB];   // [half][vox 1620][8ci f16] = 51840 B
    const int tid  = threadIdx.x;
    const int lane = tid & 63;
    const int wv   = tid >> 6;
    const int b    = blockIdx.z;
    const int z0   = blockIdx.y * 3;
    const int xti  = blockIdx.x % 6;
    const int yti  = blockIdx.x / 6;
    const int x0   = xti * 16, y0 = yti * 16;

    // per-lane B fragments (14 x 16 B, coalesced; table is L2-resident)
    const f16x8* __restrict__ bfp = (const f16x8*)tab;
    f16x8 bfrag[14];
    #pragma unroll
    for (int c = 0; c < 14; ++c)
        bfrag[c] = bfp[(b*14 + c)*64 + lane];

    // stage halo'd tile: 32-B contiguous reads, split to two 16-B LDS halves
    const _Float16* __restrict__ xtb = xt + (size_t)b * VOX * 16;
    for (int s = tid; s < NVX; s += 256) {
        const int lz = s / PLANE;
        const int r1 = s - lz * PLANE;
        const int ly = r1 / LX;
        const int lx = r1 - ly * LX;
        const int zg = z0 - 1 + lz, yg = y0 - 1 + ly, xg = x0 - 1 + lx;
        const bool ok = ((unsigned)zg < 96u) & ((unsigned)yg < 96u) & ((unsigned)xg < 96u);
        const int zc = ok ? zg : 0, yc = ok ? yg : 0, xc = ok ? xg : 0;
        const uint4* __restrict__ p = (const uint4*)(xtb + (size_t)((zc*DD + yc)*DD + xc) * 16);
        uint4 lo = {0,0,0,0}, hi = {0,0,0,0};
        if (ok) { lo = p[0]; hi = p[1]; }
        *(uint4*)&lds[s*16]         = lo;   // ci 0..7
        *(uint4*)&lds[HALFB + s*16] = hi;   // ci 8..15
    }
    __syncthreads();

    // MFMA main loop
    const int q    = lane >> 4;
    const int m    = lane & 15;    // A-row (x offset); also D-col (cout)
    const int pbit = q & 1;
    const int hbit = q >> 1;

    const float* tabf = (const float*)tab;
    const float a_n = tabf[WS_A_F + b*8 + (m & 7)];
    const float d_n = tabf[WS_D_F + b*8 + (m & 7)];

    // even-tap byte offsets per chunk (vox*16), plane stride 324 vox
    constexpr int OFFB[14] = {0,288,576,5184,5472,5760,10368,10656,10944,
                              32,5216,10400,608,10976};

    const int com = hbit*HALFB + m*16;
    const int dA = pbit*16, dB = pbit*288, dC = pbit*5184;

    #pragma unroll
    for (int t = 0; t < 12; ++t) {
        const int zi = t >> 2;              // 0..2
        const int yi = wv*4 + (t & 3);      // 0..15
        const char* __restrict__ base = &lds[(zi*PLANE + yi*LX)*16 + com];

        f16x8 af[14];
        #pragma unroll
        for (int c = 0; c < 9; ++c)  af[c] = *(const f16x8*)(base + dA + OFFB[c]);
        #pragma unroll
        for (int c = 9; c < 12; ++c) af[c] = *(const f16x8*)(base + dB + OFFB[c]);
        af[12] = *(const f16x8*)(base + dC + OFFB[12]);
        af[13] = *(const f16x8*)(base + OFFB[13]);   // odd lanes alias tap26, B=0

        f32x4 acc0 = {0.f,0.f,0.f,0.f}, acc1 = {0.f,0.f,0.f,0.f};
        #pragma unroll
        for (int c = 0; c < 14; c += 2) {
            acc0 = __builtin_amdgcn_mfma_f32_16x16x32_f16(af[c],   bfrag[c],   acc0, 0, 0, 0);
            acc1 = __builtin_amdgcn_mfma_f32_16x16x32_f16(af[c+1], bfrag[c+1], acc1, 0, 0, 0);
        }

        if (m < 8) {  // D cols 8..15 are padding
            const int zz = z0 + zi, yy = y0 + yi;
            float* __restrict__ op = out + (size_t)(b*COUT + m)*VOX
                                        + (size_t)(zz*DD + yy)*DD + x0 + q*4;
            f32x4 res;
            #pragma unroll
            for (int r = 0; r < 4; ++r) res[r] = fmaf(acc0[r] + acc1[r], a_n, d_n);
            *reinterpret_cast<f32x4*>(op) = res;
        }
    }
}

extern "C" void kernel_launch(void* const* d_in, const int* in_sizes, int n_in,
                              void* d_out, int out_size, void* d_ws, size_t ws_size,
                              hipStream_t stream) {
    const float* x    = (const float*)d_in[0];
    const float* text = (const float*)d_in[1];
    const float* wb   = (const float*)d_in[2];
    const float* bb   = (const float*)d_in[3];
    const float* rw1  = (const float*)d_in[4];
    const float* rb1  = (const float*)d_in[5];
    const float* rw2  = (const float*)d_in[6];
    const float* rb2  = (const float*)d_in[7];
    const float* mw1  = (const float*)d_in[8];
    const float* mb1  = (const float*)d_in[9];
    const float* mw2  = (const float*)d_in[10];
    const float* mb2  = (const float*)d_in[11];

    float* out = (float*)d_out;
    _Float16* xt = (_Float16*)d_ws;
    char* tab = (char*)d_ws + XT_BYTES;

    setup_kernel<<<1, 256, 0, stream>>>(text, wb, bb, rw1, rb1, rw2, rb2,
                                        mw1, mb1, mw2, mb2,
                                        out + OUT_ELEMS, tab);

    transpose_kernel<<<dim3(VOX/TV, NB), 256, 0, stream>>>(x, xt);

    conv_mfma<<<dim3(36, 32, NB), 256, 0, stream>>>(xt, tab, out);
}

// Round 4
// 266.205 us; speedup vs baseline: 1.3095x; 1.0895x over previous
//
#include <hip/hip_runtime.h>
#include <math.h>

// Problem constants
#define NB 2
#define CIN 16
#define COUT 8
#define DD 96
#define TDIM 256
#define NE 8
#define VOX (DD*DD*DD)          // 884736
#define OUT_ELEMS (NB*COUT*VOX) // 14155776

// ---- workspace layout ----
// [0, XT_BYTES): xt, f16 channels-last [b][vox][ci16] = 32 B / voxel
// [XT_BYTES, +28672): B-fragment table f16 [b][chunk14][lane64][j8]
// then floats at f32-offset 7168: a[b][co]; 7184: d[b][co]
#define XT_BYTES ((size_t)NB * VOX * 32)
#define WS_A_F 7168
#define WS_D_F 7184

// conv LDS tile: 16x*16y*3z outputs, halo -> 18*18*5 voxels
#define LX 18
#define PLANE (LX*LX)           // 324
#define NVX (PLANE*5)           // 1620
#define HALFB (NVX*16)          // 25920 B per ci-half ([vox][8ci] f16)

#define TV 1024                 // transpose voxels per block
#define NTB (VOX/TV)            // 864

typedef _Float16 f16x8 __attribute__((ext_vector_type(8)));
typedef _Float16 f16x4 __attribute__((ext_vector_type(4)));
typedef float f32x4 __attribute__((ext_vector_type(4)));

// ---------------- fused transpose + setup ----------------
// Grid (NTB+1, NB). Block (NTB, b) runs the setup path for batch b.
__global__ __launch_bounds__(256) void transpose_setup(
    const float* __restrict__ x, _Float16* __restrict__ xt,
    const float* __restrict__ text,
    const float* __restrict__ wb,    // [E,COUT,CIN,27]
    const float* __restrict__ bb,    // [E,COUT]
    const float* __restrict__ rw1, const float* __restrict__ rb1,
    const float* __restrict__ rw2, const float* __restrict__ rb2,
    const float* __restrict__ mw1, const float* __restrict__ mb1,
    const float* __restrict__ mw2, const float* __restrict__ mb2,
    float* __restrict__ dout_tail,   // d_out + OUT_ELEMS
    char* __restrict__ tab)          // ws + XT_BYTES
{
    __shared__ _Float16 buf[CIN][TV];    // 32 KB (transpose path)
    __shared__ float hg[2][64], logits[NE], rwv[NE];
    const int t = threadIdx.x;
    const int b = blockIdx.y;

    if (blockIdx.x == NTB) {
        // ---------- setup path (one block per batch) ----------
        if (t < 128) {
            const int which = t >> 6, j = t & 63;     // 0=router,1=modulator
            const float* w1 = which ? mw1 : rw1;
            const float* b1 = which ? mb1 : rb1;
            float acc = b1[j];
            for (int k = 0; k < TDIM; ++k) acc = fmaf(text[b*TDIM + k], w1[k*64 + j], acc);
            hg[which][j] = (acc >= 0.f) ? acc : 0.1f * acc;
        }
        __syncthreads();
        if (t < NE) {
            float acc = rb2[t];
            for (int k = 0; k < 64; ++k) acc = fmaf(hg[0][k], rw2[k*NE + t], acc);
            logits[t] = acc;
            dout_tail[b*NE + t] = acc;                // router_logits
        }
        __syncthreads();
        if (t < NE) {
            float mx = logits[0];
            for (int k = 1; k < NE; ++k) mx = fmaxf(mx, logits[k]);
            float s = 0.f;
            for (int k = 0; k < NE; ++k) s += expf(logits[k] - mx);
            const float w = expf(logits[t] - mx) / s;
            rwv[t] = w;
            dout_tail[NB*NE + b*NE + t] = w;          // routing_weights
        }
        __syncthreads();
        if (t < COUT) {
            float acc = mb2[t];
            for (int k = 0; k < 64; ++k) acc = fmaf(hg[1][k], mw2[k*COUT + t], acc);
            const float gamma = 1.f / (1.f + expf(-acc));
            const float a = 1.f + gamma;
            float cb = 0.f;
            for (int e = 0; e < NE; ++e) cb = fmaf(rwv[e], bb[e*COUT + t], cb);
            ((float*)tab)[WS_A_F + b*COUT + t] = a;
            ((float*)tab)[WS_D_F + b*COUT + t] = cb * a;
        }
        // bake per-lane MFMA B-fragments for this batch: r = (c*64 + lane)*8 + j
        for (int r = t; r < 14*64*8; r += 256) {
            const int c  = r >> 9;
            const int l  = (r >> 3) & 63;
            const int j  = r & 7;
            const int q  = l >> 4;
            const int n  = l & 15;       // output column = cout (cols 8..15 zero)
            const int p  = q & 1;        // tap parity within chunk
            const int ci = (q >> 1)*8 + j;
            int tap;
            if (c < 9)        tap = (c/3)*9 + (c%3)*3 + p;
            else if (c < 12)  tap = (c-9)*9 + p*3 + 2;
            else if (c == 12) tap = p*9 + 8;
            else              tap = p ? -1 : 26;
            float v = 0.f;
            if (n < 8 && tap >= 0) {
                for (int e = 0; e < NE; ++e)
                    v = fmaf(rwv[e], wb[((e*COUT + n)*CIN + ci)*27 + tap], v);
            }
            ((_Float16*)tab)[b*7168 + r] = (_Float16)v;
        }
        return;
    }

    // ---------- transpose path: x f32 [b][ci][vox] -> xt f16 [b][vox][ci16] ----------
    const int v0 = blockIdx.x * TV;
    const float* __restrict__ xb = x + (size_t)b * CIN * VOX + v0;

    #pragma unroll
    for (int ci = 0; ci < CIN; ++ci) {
        const float4 f = ((const float4*)(xb + (size_t)ci * VOX))[t];
        f16x4 hv;
        hv[0] = (_Float16)f.x; hv[1] = (_Float16)f.y;
        hv[2] = (_Float16)f.z; hv[3] = (_Float16)f.w;
        *(f16x4*)&buf[ci][t*4] = hv;
    }
    __syncthreads();

    #pragma unroll
    for (int i = 0; i < TV/256; ++i) {
        const int v = i*256 + t;
        union { _Float16 h[16]; uint4 u[2]; } o;
        #pragma unroll
        for (int ci = 0; ci < CIN; ++ci) o.h[ci] = buf[ci][v];
        uint4* __restrict__ dst = (uint4*)(xt + (size_t)(b*VOX + v0 + v) * 16);
        dst[0] = o.u[0];
        dst[1] = o.u[1];
    }
}

// ---------------- conv: implicit-GEMM f16 MFMA, rolling-plane frag reuse ----------------
// Block = 256 thr (4 waves), tile 16x*16y*3z. Grid = (36, 32, 2).
__global__ __launch_bounds__(256) void conv_mfma(
    const _Float16* __restrict__ xt,   // [b][vox][16] f16
    const char* __restrict__ tab,
    float* __restrict__ out)
{
    __shared__ char lds[2*HALFB];   // [half][vox 1620][8ci f16] = 51840 B
    const int tid  = threadIdx.x;
    const int lane = tid & 63;
    const int wv   = tid >> 6;
    const int b    = blockIdx.z;
    const int z0   = blockIdx.y * 3;
    const int xti  = blockIdx.x % 6;
    const int yti  = blockIdx.x / 6;
    const int x0   = xti * 16, y0 = yti * 16;

    // per-lane B fragments (14 x 16 B, coalesced; table is L2-resident)
    const f16x8* __restrict__ bfp = (const f16x8*)tab;
    f16x8 bfrag[14];
    #pragma unroll
    for (int c = 0; c < 14; ++c)
        bfrag[c] = bfp[(b*14 + c)*64 + lane];

    // stage halo'd tile: 32-B contiguous reads, split to two 16-B LDS halves
    const _Float16* __restrict__ xtb = xt + (size_t)b * VOX * 16;
    for (int s = tid; s < NVX; s += 256) {
        const int lz = s / PLANE;
        const int r1 = s - lz * PLANE;
        const int ly = r1 / LX;
        const int lx = r1 - ly * LX;
        const int zg = z0 - 1 + lz, yg = y0 - 1 + ly, xg = x0 - 1 + lx;
        const bool ok = ((unsigned)zg < 96u) & ((unsigned)yg < 96u) & ((unsigned)xg < 96u);
        const int zc = ok ? zg : 0, yc = ok ? yg : 0, xc = ok ? xg : 0;
        const uint4* __restrict__ p = (const uint4*)(xtb + (size_t)((zc*DD + yc)*DD + xc) * 16);
        uint4 lo = {0,0,0,0}, hi = {0,0,0,0};
        if (ok) { lo = p[0]; hi = p[1]; }
        *(uint4*)&lds[s*16]         = lo;   // ci 0..7
        *(uint4*)&lds[HALFB + s*16] = hi;   // ci 8..15
    }
    __syncthreads();

    // MFMA main loop
    const int q    = lane >> 4;
    const int m    = lane & 15;    // A-row (x offset); also D-col (cout)
    const int pbit = q & 1;
    const int hbit = q >> 1;

    const float* tabf = (const float*)tab;
    const float a_n = tabf[WS_A_F + b*8 + (m & 7)];
    const float d_n = tabf[WS_D_F + b*8 + (m & 7)];

    const int com = hbit*HALFB + m*16;
    const int dA = pbit*16;        // dx parity (A chunks 0..8)
    const int dB = pbit*288;       // dy parity (G chunks 9..11)
    const int dC = pbit*5184;      // dz parity (H12 chunk)

    #define LD_A(p_, dy_)  (*(const f16x8*)&lds[((p_)*PLANE + (yi+(dy_))*LX)*16 + com + dA])
    #define LD_G(p_)       (*(const f16x8*)&lds[((p_)*PLANE + yi*LX + 2)*16 + com + dB])
    #define LD_H12(zi_)    (*(const f16x8*)&lds[((zi_)*PLANE + (yi+2)*LX + 2)*16 + com + dC])
    #define LD_H13(zi_)    (*(const f16x8*)&lds[(((zi_)+2)*PLANE + (yi+2)*LX + 2)*16 + com])

    #pragma unroll
    for (int yi4 = 0; yi4 < 4; ++yi4) {
        const int yi = wv*4 + yi4;

        f16x8 A[3][3], G[3];
        #pragma unroll
        for (int dy = 0; dy < 3; ++dy) { A[0][dy] = LD_A(0, dy); A[1][dy] = LD_A(1, dy); }
        G[0] = LD_G(0); G[1] = LD_G(1);

        #pragma unroll
        for (int zi = 0; zi < 3; ++zi) {
            #pragma unroll
            for (int dy = 0; dy < 3; ++dy) A[2][dy] = LD_A(zi+2, dy);
            G[2] = LD_G(zi+2);
            const f16x8 H12v = LD_H12(zi);
            const f16x8 H13v = LD_H13(zi);   // odd-parity lanes alias (B=0 there)

            f32x4 acc0 = {0.f,0.f,0.f,0.f}, acc1 = {0.f,0.f,0.f,0.f};
            acc0 = __builtin_amdgcn_mfma_f32_16x16x32_f16(A[0][0], bfrag[0],  acc0, 0,0,0);
            acc1 = __builtin_amdgcn_mfma_f32_16x16x32_f16(A[0][1], bfrag[1],  acc1, 0,0,0);
            acc0 = __builtin_amdgcn_mfma_f32_16x16x32_f16(A[0][2], bfrag[2],  acc0, 0,0,0);
            acc1 = __builtin_amdgcn_mfma_f32_16x16x32_f16(A[1][0], bfrag[3],  acc1, 0,0,0);
            acc0 = __builtin_amdgcn_mfma_f32_16x16x32_f16(A[1][1], bfrag[4],  acc0, 0,0,0);
            acc1 = __builtin_amdgcn_mfma_f32_16x16x32_f16(A[1][2], bfrag[5],  acc1, 0,0,0);
            acc0 = __builtin_amdgcn_mfma_f32_16x16x32_f16(A[2][0], bfrag[6],  acc0, 0,0,0);
            acc1 = __builtin_amdgcn_mfma_f32_16x16x32_f16(A[2][1], bfrag[7],  acc1, 0,0,0);
            acc0 = __builtin_amdgcn_mfma_f32_16x16x32_f16(A[2][2], bfrag[8],  acc0, 0,0,0);
            acc1 = __builtin_amdgcn_mfma_f32_16x16x32_f16(G[0],    bfrag[9],  acc1, 0,0,0);
            acc0 = __builtin_amdgcn_mfma_f32_16x16x32_f16(G[1],    bfrag[10], acc0, 0,0,0);
            acc1 = __builtin_amdgcn_mfma_f32_16x16x32_f16(G[2],    bfrag[11], acc1, 0,0,0);
            acc0 = __builtin_amdgcn_mfma_f32_16x16x32_f16(H12v,    bfrag[12], acc0, 0,0,0);
            acc1 = __builtin_amdgcn_mfma_f32_16x16x32_f16(H13v,    bfrag[13], acc1, 0,0,0);

            if (m < 8) {  // D cols 8..15 are padding
                const int zz = z0 + zi, yy = y0 + yi;
                float* __restrict__ op = out + (size_t)(b*COUT + m)*VOX
                                            + (size_t)(zz*DD + yy)*DD + x0 + q*4;
                f32x4 res;
                #pragma unroll
                for (int r = 0; r < 4; ++r) res[r] = fmaf(acc0[r] + acc1[r], a_n, d_n);
                *reinterpret_cast<f32x4*>(op) = res;
            }

            // rotate plane cache
            #pragma unroll
            for (int dy = 0; dy < 3; ++dy) { A[0][dy] = A[1][dy]; A[1][dy] = A[2][dy]; }
            G[0] = G[1]; G[1] = G[2];
        }
    }
    #undef LD_A
    #undef LD_G
    #undef LD_H12
    #undef LD_H13
}

extern "C" void kernel_launch(void* const* d_in, const int* in_sizes, int n_in,
                              void* d_out, int out_size, void* d_ws, size_t ws_size,
                              hipStream_t stream) {
    const float* x    = (const float*)d_in[0];
    const float* text = (const float*)d_in[1];
    const float* wb   = (const float*)d_in[2];
    const float* bb   = (const float*)d_in[3];
    const float* rw1  = (const float*)d_in[4];
    const float* rb1  = (const float*)d_in[5];
    const float* rw2  = (const float*)d_in[6];
    const float* rb2  = (const float*)d_in[7];
    const float* mw1  = (const float*)d_in[8];
    const float* mb1  = (const float*)d_in[9];
    const float* mw2  = (const float*)d_in[10];
    const float* mb2  = (const float*)d_in[11];

    float* out = (float*)d_out;
    _Float16* xt = (_Float16*)d_ws;
    char* tab = (char*)d_ws + XT_BYTES;

    transpose_setup<<<dim3(NTB + 1, NB), 256, 0, stream>>>(
        x, xt, text, wb, bb, rw1, rb1, rw2, rb2, mw1, mb1, mw2, mb2,
        out + OUT_ELEMS, tab);

    conv_mfma<<<dim3(36, 32, NB), 256, 0, stream>>>(xt, tab, out);
}